// Round 3
// baseline (1091.221 us; speedup 1.0000x reference)
//
#include <hip/hip_runtime.h>
#include <hip/hip_fp16.h>

#define N_NODES 50000
#define BSH 7                 // bucket = dst >> 7
#define BMASK 127
#define NBUCK 391             // ceil(50000/128)
#define EPB 8192              // edges per block in bucket hist/fill

// ---------------------------------------------------------------------------
// A1: bucket histogram. LDS hist per block, one global atomic per (blk,bucket).
// ---------------------------------------------------------------------------
__global__ __launch_bounds__(512) void k_bhist(
    const int* __restrict__ dst, int* __restrict__ bcnt, int E)
{
    __shared__ int hist[NBUCK];
    for (int i = threadIdx.x; i < NBUCK; i += 512) hist[i] = 0;
    __syncthreads();
    int base = blockIdx.x * EPB;
    int lim  = min(base + EPB, E);
    for (int e = base + threadIdx.x; e < lim; e += 512)
        atomicAdd(&hist[dst[e] >> BSH], 1);
    __syncthreads();
    for (int i = threadIdx.x; i < NBUCK; i += 512)
        if (hist[i]) atomicAdd(&bcnt[i], hist[i]);
}

// ---------------------------------------------------------------------------
// A2: exclusive scan of 391 bucket counts.
// ---------------------------------------------------------------------------
__global__ __launch_bounds__(512) void k_bscan(
    const int* __restrict__ bcnt, int* __restrict__ boff,
    int* __restrict__ bcur, int E)
{
    __shared__ int tmp[NBUCK];
    for (int i = threadIdx.x; i < NBUCK; i += 512) tmp[i] = bcnt[i];
    __syncthreads();
    if (threadIdx.x == 0) {
        int run = 0;
        for (int i = 0; i < NBUCK; ++i) { int c = tmp[i]; tmp[i] = run; run += c; }
    }
    __syncthreads();
    for (int i = threadIdx.x; i < NBUCK; i += 512) {
        boff[i] = tmp[i];
        bcur[i] = tmp[i];
    }
    if (threadIdx.x == 0) boff[NBUCK] = E;
}

// ---------------------------------------------------------------------------
// A3: bucketed fill. Payload int2 {(e<<7)|(dst&127), src[e]}. No within-bucket
// sort needed anymore — buckets are consumed by LDS-accumulator kernels.
// ---------------------------------------------------------------------------
__global__ __launch_bounds__(512) void k_bfill(
    const int* __restrict__ dst, const int* __restrict__ src,
    int* __restrict__ bcur, int2* __restrict__ ebuf, int E)
{
    __shared__ unsigned short dstv[EPB];
    __shared__ int hist[NBUCK];
    __shared__ int basev[NBUCK];
    __shared__ int cur[NBUCK];
    for (int i = threadIdx.x; i < NBUCK; i += 512) hist[i] = 0;
    __syncthreads();
    int base = blockIdx.x * EPB;
    int lim  = min(base + EPB, E);
    for (int e = base + threadIdx.x; e < lim; e += 512) {
        int d = dst[e];
        dstv[e - base] = (unsigned short)d;
        atomicAdd(&hist[d >> BSH], 1);
    }
    __syncthreads();
    for (int i = threadIdx.x; i < NBUCK; i += 512) {
        int c = hist[i];
        cur[i] = 0;
        if (c) basev[i] = atomicAdd(&bcur[i], c);
    }
    __syncthreads();
    int n = lim - base;
    for (int idx = threadIdx.x; idx < n; idx += 512) {
        int d = (int)dstv[idx];
        int b = d >> BSH;
        int p = basev[b] + atomicAdd(&cur[b], 1);
        ebuf[p] = make_int2(((base + idx) << BSH) | (d & BMASK), src[base + idx]);
    }
}

// ---------------------------------------------------------------------------
// B1: per-bucket mean accumulation. One block per bucket; stream the bucket's
// edge records, gather ef rows (compulsory 205 MB random read), ds_add_f32
// into acc[128][33] (pad => same-lane/different-row is 2-way = free), then
// divide by degree and emit fp16 mean rows (table stays L2-resident for B2).
// No stash => no bucket-capacity assumption.
// ---------------------------------------------------------------------------
__global__ __launch_bounds__(512) void k_bmean(
    const float* __restrict__ ef, const int2* __restrict__ ebuf,
    const int* __restrict__ boff, __half* __restrict__ meanh)
{
    __shared__ float acc[128][33];
    __shared__ int dcnt[128];
    const int b   = blockIdx.x;
    const int beg = boff[b];
    const int end = boff[b + 1];
    for (int i = threadIdx.x; i < 128 * 33; i += 512) ((float*)acc)[i] = 0.f;
    for (int i = threadIdx.x; i < 128; i += 512) dcnt[i] = 0;
    __syncthreads();
    const int d   = threadIdx.x & 31;
    const int grp = threadIdx.x >> 5;      // 0..15
    for (int i0 = beg + grp * 8; i0 < end; i0 += 16 * 8) {
#pragma unroll
        for (int k = 0; k < 8; ++k) {
            int i = i0 + k;
            if (i < end) {
                int2 w = ebuf[i];
                int e  = w.x >> BSH;
                int dl = w.x & BMASK;
                float v = ef[(size_t)e * 32 + d];
                atomicAdd(&acc[dl][d], v);
                if (d == 0) atomicAdd(&dcnt[dl], 1);
            }
        }
    }
    __syncthreads();
    const int n0 = b << BSH;
    for (int idx = threadIdx.x; idx < 128 * 32; idx += 512) {
        int dl = idx >> 5, dd = idx & 31;
        int n = n0 + dl;
        if (n < N_NODES)
            meanh[(size_t)n * 32 + dd] =
                __float2half(acc[dl][dd] / fmaxf((float)dcnt[dl], 1.0f));
    }
}

// ---------------------------------------------------------------------------
// B2: per-bucket h accumulation + linear. Stream the bucket's edge records,
// gather L2-resident fp16 mean rows by src (64 B/edge), ds_add_f32 into
// acc[128][33], then g = acc @ W^T (32x32) with coalesced f32 stores.
// ---------------------------------------------------------------------------
__global__ __launch_bounds__(512) void k_bhg(
    const __half* __restrict__ meanh, const int2* __restrict__ ebuf,
    const int* __restrict__ boff, const float* __restrict__ W,
    float* __restrict__ g)
{
    __shared__ float acc[128][33];
    const int b   = blockIdx.x;
    const int beg = boff[b];
    const int end = boff[b + 1];
    for (int i = threadIdx.x; i < 128 * 33; i += 512) ((float*)acc)[i] = 0.f;
    __syncthreads();
    const int d   = threadIdx.x & 31;
    const int grp = threadIdx.x >> 5;      // 0..15
    for (int i0 = beg + grp * 8; i0 < end; i0 += 16 * 8) {
#pragma unroll
        for (int k = 0; k < 8; ++k) {
            int i = i0 + k;
            if (i < end) {
                int2 w = ebuf[i];
                int dl = w.x & BMASK;
                int s  = w.y;
                float v = __half2float(meanh[(size_t)s * 32 + d]);
                atomicAdd(&acc[dl][d], v);
            }
        }
    }
    __syncthreads();
    // ---- g = acc @ W^T for the bucket's 128 nodes
    const int j  = threadIdx.x & 31;
    const int rb = threadIdx.x >> 5;       // 0..15
    float w[32];
#pragma unroll
    for (int k = 0; k < 8; ++k) {
        float4 wv = *(const float4*)(W + j * 32 + k * 4);
        w[4 * k + 0] = wv.x;
        w[4 * k + 1] = wv.y;
        w[4 * k + 2] = wv.z;
        w[4 * k + 3] = wv.w;
    }
    const int n0 = b << BSH;
#pragma unroll
    for (int r = 0; r < 8; ++r) {
        int row = rb + 16 * r;             // 0..127
        float a = 0.f;
#pragma unroll
        for (int dd = 0; dd < 32; ++dd) a += acc[row][dd] * w[dd];
        int n = n0 + row;
        if (n < N_NODES) g[(size_t)n * 32 + j] = a;
    }
}

// ---------------------------------------------------------------------------
// C3: out[e] = 0.5*(g[src]+g[dst]) + b. 8 lanes x float4 per edge;
// fully coalesced 128B output runs.
// ---------------------------------------------------------------------------
__global__ __launch_bounds__(256) void k_edge_out2(
    const float* __restrict__ g, const int* __restrict__ src,
    const int* __restrict__ dst, const float* __restrict__ b,
    float* __restrict__ out, int E)
{
    int t = blockIdx.x * 256 + threadIdx.x;
    int e = t >> 3;
    if (e >= E) return;
    int d4 = (t & 7) << 2;
    int s = src[e];
    int n = dst[e];
    float4 a  = *(const float4*)(g + (size_t)s * 32 + d4);
    float4 c  = *(const float4*)(g + (size_t)n * 32 + d4);
    float4 bv = *(const float4*)(b + d4);
    float4 o;
    o.x = 0.5f * (a.x + c.x) + bv.x;
    o.y = 0.5f * (a.y + c.y) + bv.y;
    o.z = 0.5f * (a.z + c.z) + bv.z;
    o.w = 0.5f * (a.w + c.w) + bv.w;
    *(float4*)(out + (size_t)e * 32 + d4) = o;
}

extern "C" void kernel_launch(void* const* d_in, const int* in_sizes, int n_in,
                              void* d_out, int out_size, void* d_ws, size_t ws_size,
                              hipStream_t stream)
{
    const float* ef  = (const float*)d_in[0];
    const int*   src = (const int*)d_in[1];
    const int*   dst = (const int*)d_in[2];
    const float* W   = (const float*)d_in[3];
    const float* b   = (const float*)d_in[4];
    float*       out = (float*)d_out;
    const int E = in_sizes[1];

    // ---- workspace carve (16B-aligned chunks) ----
    int*    bcnt  = (int*)d_ws;           // 512
    int*    boff  = bcnt + 512;           // 512 (NBUCK+1 used)
    int*    bcur  = boff + 512;           // 512
    int2*   ebuf2 = (int2*)(bcur + 512);  // E int2 (8B aligned)
    __half* meanh = (__half*)(ebuf2 + E); // N*32 halves (3.2 MB)
    float*  g     = (float*)((char*)meanh + (size_t)N_NODES * 32 * sizeof(__half));

    hipMemsetAsync(bcnt, 0, 512 * sizeof(int), stream);

    const int abk = (E + EPB - 1) / EPB;   // 196
    k_bhist<<<abk, 512, 0, stream>>>(dst, bcnt, E);
    k_bscan<<<1, 512, 0, stream>>>(bcnt, boff, bcur, E);
    k_bfill<<<abk, 512, 0, stream>>>(dst, src, bcur, ebuf2, E);

    k_bmean<<<NBUCK, 512, 0, stream>>>(ef, ebuf2, boff, meanh);
    k_bhg<<<NBUCK, 512, 0, stream>>>(meanh, ebuf2, boff, W, g);

    const int oblk = (E * 8 + 255) / 256;
    k_edge_out2<<<oblk, 256, 0, stream>>>(g, src, dst, b, out, E);
}

// Round 4
// 973.974 us; speedup vs baseline: 1.1204x; 1.1204x over previous
//
#include <hip/hip_runtime.h>
#include <hip/hip_fp16.h>

#define N_NODES 50000
#define BSH 7                 // bucket = dst >> 7
#define BMASK 127
#define NBUCK 391             // ceil(50000/128)
#define EPB 8192              // edges per block in bucket hist/fill
#define SPLIT 4               // sub-blocks per bucket in accumulate kernels

// ---------------------------------------------------------------------------
// A1: bucket histogram. LDS hist per block, one global atomic per (blk,bucket).
// ---------------------------------------------------------------------------
__global__ __launch_bounds__(512) void k_bhist(
    const int* __restrict__ dst, int* __restrict__ bcnt, int E)
{
    __shared__ int hist[NBUCK];
    for (int i = threadIdx.x; i < NBUCK; i += 512) hist[i] = 0;
    __syncthreads();
    int base = blockIdx.x * EPB;
    int lim  = min(base + EPB, E);
    for (int e = base + threadIdx.x; e < lim; e += 512)
        atomicAdd(&hist[dst[e] >> BSH], 1);
    __syncthreads();
    for (int i = threadIdx.x; i < NBUCK; i += 512)
        if (hist[i]) atomicAdd(&bcnt[i], hist[i]);
}

// ---------------------------------------------------------------------------
// A2: exclusive scan of 391 bucket counts.
// ---------------------------------------------------------------------------
__global__ __launch_bounds__(512) void k_bscan(
    const int* __restrict__ bcnt, int* __restrict__ boff,
    int* __restrict__ bcur, int E)
{
    __shared__ int tmp[NBUCK];
    for (int i = threadIdx.x; i < NBUCK; i += 512) tmp[i] = bcnt[i];
    __syncthreads();
    if (threadIdx.x == 0) {
        int run = 0;
        for (int i = 0; i < NBUCK; ++i) { int c = tmp[i]; tmp[i] = run; run += c; }
    }
    __syncthreads();
    for (int i = threadIdx.x; i < NBUCK; i += 512) {
        boff[i] = tmp[i];
        bcur[i] = tmp[i];
    }
    if (threadIdx.x == 0) boff[NBUCK] = E;
}

// ---------------------------------------------------------------------------
// A3: bucketed fill. Payload int2 {(e<<7)|(dst&127), src[e]}.
// ---------------------------------------------------------------------------
__global__ __launch_bounds__(512) void k_bfill(
    const int* __restrict__ dst, const int* __restrict__ src,
    int* __restrict__ bcur, int2* __restrict__ ebuf, int E)
{
    __shared__ unsigned short dstv[EPB];
    __shared__ int hist[NBUCK];
    __shared__ int basev[NBUCK];
    __shared__ int cur[NBUCK];
    for (int i = threadIdx.x; i < NBUCK; i += 512) hist[i] = 0;
    __syncthreads();
    int base = blockIdx.x * EPB;
    int lim  = min(base + EPB, E);
    for (int e = base + threadIdx.x; e < lim; e += 512) {
        int d = dst[e];
        dstv[e - base] = (unsigned short)d;
        atomicAdd(&hist[d >> BSH], 1);
    }
    __syncthreads();
    for (int i = threadIdx.x; i < NBUCK; i += 512) {
        int c = hist[i];
        cur[i] = 0;
        if (c) basev[i] = atomicAdd(&bcur[i], c);
    }
    __syncthreads();
    int n = lim - base;
    for (int idx = threadIdx.x; idx < n; idx += 512) {
        int d = (int)dstv[idx];
        int b = d >> BSH;
        int p = basev[b] + atomicAdd(&cur[b], 1);
        ebuf[p] = make_int2(((base + idx) << BSH) | (d & BMASK), src[base + idx]);
    }
}

// ---------------------------------------------------------------------------
// B1: bucket-split mean accumulation. Grid = NBUCK x SPLIT; each sub-block
// owns 1/SPLIT of its bucket's edges, accumulates into LDS acc[128][33] via
// ds_add_f32, then WRITES its partial slice (no global atomics) + adds its
// partial degree counts. Inner loop: hoisted unguarded 8-chunk loads so the
// compiler keeps 8 HBM row-reads in flight (round-3 failure: guarded
// per-element load+atomic collapsed to VGPR=8 serial chain).
// ---------------------------------------------------------------------------
__global__ __launch_bounds__(512) void k_bmean(
    const float* __restrict__ ef, const int2* __restrict__ ebuf,
    const int* __restrict__ boff, float* __restrict__ mpart,
    int* __restrict__ deg)
{
    __shared__ float acc[128][33];
    __shared__ int dcnt[128];
    const int b   = blockIdx.x;
    const int s   = blockIdx.y;
    const int beg = boff[b];
    const int cnt = boff[b + 1] - beg;
    const int s0  = beg + (int)(((long long)cnt * s) / SPLIT);
    const int s1  = beg + (int)(((long long)cnt * (s + 1)) / SPLIT);
    for (int i = threadIdx.x; i < 128 * 33; i += 512) ((float*)acc)[i] = 0.f;
    for (int i = threadIdx.x; i < 128; i += 512) dcnt[i] = 0;
    __syncthreads();
    const int d   = threadIdx.x & 31;
    const int grp = threadIdx.x >> 5;      // 0..15
    for (int c0 = s0 + grp * 8; c0 + 8 <= s1; c0 += 16 * 8) {
        int2 w0 = ebuf[c0 + 0], w1 = ebuf[c0 + 1], w2 = ebuf[c0 + 2], w3 = ebuf[c0 + 3];
        int2 w4 = ebuf[c0 + 4], w5 = ebuf[c0 + 5], w6 = ebuf[c0 + 6], w7 = ebuf[c0 + 7];
        float v0 = ef[(size_t)(w0.x >> BSH) * 32 + d];
        float v1 = ef[(size_t)(w1.x >> BSH) * 32 + d];
        float v2 = ef[(size_t)(w2.x >> BSH) * 32 + d];
        float v3 = ef[(size_t)(w3.x >> BSH) * 32 + d];
        float v4 = ef[(size_t)(w4.x >> BSH) * 32 + d];
        float v5 = ef[(size_t)(w5.x >> BSH) * 32 + d];
        float v6 = ef[(size_t)(w6.x >> BSH) * 32 + d];
        float v7 = ef[(size_t)(w7.x >> BSH) * 32 + d];
        atomicAdd(&acc[w0.x & BMASK][d], v0);
        atomicAdd(&acc[w1.x & BMASK][d], v1);
        atomicAdd(&acc[w2.x & BMASK][d], v2);
        atomicAdd(&acc[w3.x & BMASK][d], v3);
        atomicAdd(&acc[w4.x & BMASK][d], v4);
        atomicAdd(&acc[w5.x & BMASK][d], v5);
        atomicAdd(&acc[w6.x & BMASK][d], v6);
        atomicAdd(&acc[w7.x & BMASK][d], v7);
        if (d == 0) {
            atomicAdd(&dcnt[w0.x & BMASK], 1);
            atomicAdd(&dcnt[w1.x & BMASK], 1);
            atomicAdd(&dcnt[w2.x & BMASK], 1);
            atomicAdd(&dcnt[w3.x & BMASK], 1);
            atomicAdd(&dcnt[w4.x & BMASK], 1);
            atomicAdd(&dcnt[w5.x & BMASK], 1);
            atomicAdd(&dcnt[w6.x & BMASK], 1);
            atomicAdd(&dcnt[w7.x & BMASK], 1);
        }
    }
    // tail: < 8 edges, group g handles element g
    int nfull = ((s1 - s0) >> 3) << 3;
    int ti = s0 + nfull + grp;
    if (ti < s1) {
        int2 w = ebuf[ti];
        float v = ef[(size_t)(w.x >> BSH) * 32 + d];
        atomicAdd(&acc[w.x & BMASK][d], v);
        if (d == 0) atomicAdd(&dcnt[w.x & BMASK], 1);
    }
    __syncthreads();
    const int n0 = b << BSH;
    float* mp = mpart + (size_t)s * N_NODES * 32;
    for (int idx = threadIdx.x; idx < 128 * 32; idx += 512) {
        int dl = idx >> 5, dd = idx & 31;
        int n = n0 + dl;
        if (n < N_NODES) mp[(size_t)n * 32 + dd] = acc[dl][dd];
    }
    for (int dl = threadIdx.x; dl < 128; dl += 512) {
        int n = n0 + dl;
        if (n < N_NODES && dcnt[dl]) atomicAdd(&deg[n], dcnt[dl]);
    }
}

// ---------------------------------------------------------------------------
// B1b: combine SPLIT mean partials, divide by degree, emit fp16 mean
// (3.2 MB table -> L2-resident for B2's gather).
// ---------------------------------------------------------------------------
__global__ __launch_bounds__(512) void k_mfin(
    const float* __restrict__ mpart, const int* __restrict__ deg,
    __half* __restrict__ meanh)
{
    int idx = blockIdx.x * 512 + threadIdx.x;
    if (idx >= N_NODES * 32) return;
    int n = idx >> 5;
    float sum = mpart[idx]
              + mpart[(size_t)N_NODES * 32 + idx]
              + mpart[(size_t)2 * N_NODES * 32 + idx]
              + mpart[(size_t)3 * N_NODES * 32 + idx];
    meanh[idx] = __float2half(sum / fmaxf((float)deg[n], 1.0f));
}

// ---------------------------------------------------------------------------
// B2: bucket-split h accumulation. Same structure as B1; gathers L2-resident
// fp16 mean rows by src (carried in the payload), writes hpart slices.
// ---------------------------------------------------------------------------
__global__ __launch_bounds__(512) void k_bhg(
    const __half* __restrict__ meanh, const int2* __restrict__ ebuf,
    const int* __restrict__ boff, float* __restrict__ hpart)
{
    __shared__ float acc[128][33];
    const int b   = blockIdx.x;
    const int s   = blockIdx.y;
    const int beg = boff[b];
    const int cnt = boff[b + 1] - beg;
    const int s0  = beg + (int)(((long long)cnt * s) / SPLIT);
    const int s1  = beg + (int)(((long long)cnt * (s + 1)) / SPLIT);
    for (int i = threadIdx.x; i < 128 * 33; i += 512) ((float*)acc)[i] = 0.f;
    __syncthreads();
    const int d   = threadIdx.x & 31;
    const int grp = threadIdx.x >> 5;      // 0..15
    for (int c0 = s0 + grp * 8; c0 + 8 <= s1; c0 += 16 * 8) {
        int2 w0 = ebuf[c0 + 0], w1 = ebuf[c0 + 1], w2 = ebuf[c0 + 2], w3 = ebuf[c0 + 3];
        int2 w4 = ebuf[c0 + 4], w5 = ebuf[c0 + 5], w6 = ebuf[c0 + 6], w7 = ebuf[c0 + 7];
        float v0 = __half2float(meanh[(size_t)w0.y * 32 + d]);
        float v1 = __half2float(meanh[(size_t)w1.y * 32 + d]);
        float v2 = __half2float(meanh[(size_t)w2.y * 32 + d]);
        float v3 = __half2float(meanh[(size_t)w3.y * 32 + d]);
        float v4 = __half2float(meanh[(size_t)w4.y * 32 + d]);
        float v5 = __half2float(meanh[(size_t)w5.y * 32 + d]);
        float v6 = __half2float(meanh[(size_t)w6.y * 32 + d]);
        float v7 = __half2float(meanh[(size_t)w7.y * 32 + d]);
        atomicAdd(&acc[w0.x & BMASK][d], v0);
        atomicAdd(&acc[w1.x & BMASK][d], v1);
        atomicAdd(&acc[w2.x & BMASK][d], v2);
        atomicAdd(&acc[w3.x & BMASK][d], v3);
        atomicAdd(&acc[w4.x & BMASK][d], v4);
        atomicAdd(&acc[w5.x & BMASK][d], v5);
        atomicAdd(&acc[w6.x & BMASK][d], v6);
        atomicAdd(&acc[w7.x & BMASK][d], v7);
    }
    int nfull = ((s1 - s0) >> 3) << 3;
    int ti = s0 + nfull + grp;
    if (ti < s1) {
        int2 w = ebuf[ti];
        float v = __half2float(meanh[(size_t)w.y * 32 + d]);
        atomicAdd(&acc[w.x & BMASK][d], v);
    }
    __syncthreads();
    const int n0 = b << BSH;
    float* hp = hpart + (size_t)s * N_NODES * 32;
    for (int idx = threadIdx.x; idx < 128 * 32; idx += 512) {
        int dl = idx >> 5, dd = idx & 31;
        int n = n0 + dl;
        if (n < N_NODES) hp[(size_t)n * 32 + dd] = acc[dl][dd];
    }
}

// ---------------------------------------------------------------------------
// B2b: combine SPLIT h partials + 32x32 matmul g = h @ W^T. 32 nodes/block.
// ---------------------------------------------------------------------------
__global__ __launch_bounds__(256) void k_gfin(
    const float* __restrict__ hpart, const float* __restrict__ W,
    float* __restrict__ g)
{
    __shared__ float sh[32][36];
    const int t  = threadIdx.x;
    const int n0 = blockIdx.x * 32;
    for (int idx = t; idx < 32 * 32; idx += 256) {
        int r = idx >> 5, dd = idx & 31;
        int n = n0 + r;
        float sum = 0.f;
        if (n < N_NODES) {
            size_t o = (size_t)n * 32 + dd;
            sum = hpart[o]
                + hpart[(size_t)N_NODES * 32 + o]
                + hpart[(size_t)2 * N_NODES * 32 + o]
                + hpart[(size_t)3 * N_NODES * 32 + o];
        }
        sh[r][dd] = sum;
    }
    __syncthreads();
    const int j  = t & 31;
    const int rb = t >> 5;
    float w[32];
#pragma unroll
    for (int k = 0; k < 8; ++k) {
        float4 wv = *(const float4*)(W + j * 32 + k * 4);
        w[4 * k + 0] = wv.x;
        w[4 * k + 1] = wv.y;
        w[4 * k + 2] = wv.z;
        w[4 * k + 3] = wv.w;
    }
    float a0 = 0.f, a1 = 0.f, a2 = 0.f, a3 = 0.f;
#pragma unroll
    for (int dd = 0; dd < 32; ++dd) {
        float wd = w[dd];
        a0 += sh[rb +  0][dd] * wd;
        a1 += sh[rb +  8][dd] * wd;
        a2 += sh[rb + 16][dd] * wd;
        a3 += sh[rb + 24][dd] * wd;
    }
    if (n0 + rb +  0 < N_NODES) g[(size_t)(n0 + rb +  0) * 32 + j] = a0;
    if (n0 + rb +  8 < N_NODES) g[(size_t)(n0 + rb +  8) * 32 + j] = a1;
    if (n0 + rb + 16 < N_NODES) g[(size_t)(n0 + rb + 16) * 32 + j] = a2;
    if (n0 + rb + 24 < N_NODES) g[(size_t)(n0 + rb + 24) * 32 + j] = a3;
}

// ---------------------------------------------------------------------------
// C3: out[e] = 0.5*(g[src]+g[dst]) + b. 8 lanes x float4 per edge.
// ---------------------------------------------------------------------------
__global__ __launch_bounds__(256) void k_edge_out2(
    const float* __restrict__ g, const int* __restrict__ src,
    const int* __restrict__ dst, const float* __restrict__ b,
    float* __restrict__ out, int E)
{
    int t = blockIdx.x * 256 + threadIdx.x;
    int e = t >> 3;
    if (e >= E) return;
    int d4 = (t & 7) << 2;
    int s = src[e];
    int n = dst[e];
    float4 a  = *(const float4*)(g + (size_t)s * 32 + d4);
    float4 c  = *(const float4*)(g + (size_t)n * 32 + d4);
    float4 bv = *(const float4*)(b + d4);
    float4 o;
    o.x = 0.5f * (a.x + c.x) + bv.x;
    o.y = 0.5f * (a.y + c.y) + bv.y;
    o.z = 0.5f * (a.z + c.z) + bv.z;
    o.w = 0.5f * (a.w + c.w) + bv.w;
    *(float4*)(out + (size_t)e * 32 + d4) = o;
}

extern "C" void kernel_launch(void* const* d_in, const int* in_sizes, int n_in,
                              void* d_out, int out_size, void* d_ws, size_t ws_size,
                              hipStream_t stream)
{
    const float* ef  = (const float*)d_in[0];
    const int*   src = (const int*)d_in[1];
    const int*   dst = (const int*)d_in[2];
    const float* W   = (const float*)d_in[3];
    const float* b   = (const float*)d_in[4];
    float*       out = (float*)d_out;
    const int E = in_sizes[1];

    // ---- workspace carve ----
    int*    bcnt  = (int*)d_ws;                       // [0,512)
    int*    boff  = bcnt + 512;                       // [512,1024)
    int*    bcur  = boff + 512;                       // [1024,1536)
    int*    deg   = bcur + 512;                       // [1536, 1536+50048)
    int2*   ebuf2 = (int2*)(deg + 50048);             // byte 206336, 8B-aligned
    float*  mpart = (float*)(ebuf2 + E);              // SPLIT*N*32 f32 (25.6 MB)
    float*  hpart = mpart + (size_t)SPLIT * N_NODES * 32;  // 25.6 MB
    __half* meanh = (__half*)(hpart + (size_t)SPLIT * N_NODES * 32); // 3.2 MB
    float*  g     = (float*)((char*)meanh + (size_t)N_NODES * 32 * sizeof(__half));

    // zero bcnt + deg (and boff/bcur, overwritten anyway) in one memset
    hipMemsetAsync(bcnt, 0, (size_t)(1536 + 50048) * sizeof(int), stream);

    const int abk = (E + EPB - 1) / EPB;   // 196
    k_bhist<<<abk, 512, 0, stream>>>(dst, bcnt, E);
    k_bscan<<<1, 512, 0, stream>>>(bcnt, boff, bcur, E);
    k_bfill<<<abk, 512, 0, stream>>>(dst, src, bcur, ebuf2, E);

    dim3 bgrid(NBUCK, SPLIT);
    k_bmean<<<bgrid, 512, 0, stream>>>(ef, ebuf2, boff, mpart, deg);
    k_mfin<<<(N_NODES * 32 + 511) / 512, 512, 0, stream>>>(mpart, deg, meanh);
    k_bhg<<<bgrid, 512, 0, stream>>>(meanh, ebuf2, boff, hpart);
    k_gfin<<<(N_NODES + 31) / 32, 256, 0, stream>>>(hpart, W, g);

    const int oblk = (E * 8 + 255) / 256;
    k_edge_out2<<<oblk, 256, 0, stream>>>(g, src, dst, b, out, E);
}